// Round 1
// baseline (161.491 us; speedup 1.0000x reference)
//
#include <hip/hip_runtime.h>
#include <hip/hip_bf16.h>

#define NB 2
#define NN 20000
#define NKN 16          // neighbors per node
#define NC 128          // C_IN
#define NM 9            // M kernels
#define NO 128          // C_OUT
#define NR (NB*NN)      // 40000 rows
#define KK (NM*NC)      // 1152 GEMM reduce dim
#define NPB 32          // nodes per fused block (20000 % 32 == 0 -> no batch straddle)
#define YS 12           // padded y row stride (floats)
#define YB (NR/64)      // ycalc blocks (64 nodes each) = 625
#define QTOFF 131072u   // qT region base inside smem

typedef short bf16x8 __attribute__((ext_vector_type(8)));
typedef short bf16x4 __attribute__((ext_vector_type(4)));
typedef float f32x4  __attribute__((ext_vector_type(4)));
typedef unsigned short u16x8 __attribute__((ext_vector_type(8)));

union frg8 { bf16x4 h[2]; bf16x8 v; };

__device__ inline unsigned short bfb(float f) {
    union { __hip_bfloat16 b; unsigned short u; } t;
    t.b = __float2bfloat16(f);
    return t.u;
}

// ---------------- Kernel 1: prep ----------------
// y = x·u^T (unchanged). Wg repack: NEW K-order kk' = ct*144 + m*16 + ci
// (ct = 16-col tile of C_IN, m kernel, ci col-in-tile) so phase-A MFMA output
// tiles are K-contiguous. Wg memory layout itself unchanged: [kc][o128][k32].
__global__ __launch_bounds__(256) void prep_kernel(const float* __restrict__ x,
                                                   const float* __restrict__ u,
                                                   const float* __restrict__ W,
                                                   float* __restrict__ y,
                                                   __hip_bfloat16* __restrict__ xb,
                                                   __hip_bfloat16* __restrict__ Wg,
                                                   int use_xb) {
    int tid = threadIdx.x;
    if (blockIdx.x < YB) {
        int wave = tid >> 6, lane = tid & 63;
        int lr = lane & 15, quad = lane >> 4;
        int node0 = blockIdx.x * 64 + wave * 16;
        long xbase = (long)(node0 + lr) * NC;

        bf16x8 afr[4];
        #pragma unroll
        for (int kc = 0; kc < 4; kc++) {
            const float* px = x + xbase + kc * 32 + quad * 8;
            float4 a0 = *(const float4*)px;
            float4 a1 = *(const float4*)(px + 4);
            union { bf16x8 v; unsigned short s[8]; __hip_bfloat16 h[8]; } af;
            af.h[0] = __float2bfloat16(a0.x); af.h[1] = __float2bfloat16(a0.y);
            af.h[2] = __float2bfloat16(a0.z); af.h[3] = __float2bfloat16(a0.w);
            af.h[4] = __float2bfloat16(a1.x); af.h[5] = __float2bfloat16(a1.y);
            af.h[6] = __float2bfloat16(a1.z); af.h[7] = __float2bfloat16(a1.w);
            afr[kc] = af.v;
            if (use_xb)
                *(u16x8*)((unsigned short*)xb + xbase + kc * 32 + quad * 8) =
                    *(u16x8*)&af.v;
        }
        int cs = (lr < NM) ? lr : 0;
        float fz = (lr < NM) ? 1.f : 0.f;
        f32x4 acc = (f32x4){0.f, 0.f, 0.f, 0.f};
        #pragma unroll
        for (int kc = 0; kc < 4; kc++) {
            const float* pu = u + cs * NC + kc * 32 + quad * 8;
            float4 b0 = *(const float4*)pu;
            float4 b1 = *(const float4*)(pu + 4);
            union { bf16x8 v; __hip_bfloat16 h[8]; } bf;
            bf.h[0] = __float2bfloat16(b0.x * fz); bf.h[1] = __float2bfloat16(b0.y * fz);
            bf.h[2] = __float2bfloat16(b0.z * fz); bf.h[3] = __float2bfloat16(b0.w * fz);
            bf.h[4] = __float2bfloat16(b1.x * fz); bf.h[5] = __float2bfloat16(b1.y * fz);
            bf.h[6] = __float2bfloat16(b1.z * fz); bf.h[7] = __float2bfloat16(b1.w * fz);
            acc = __builtin_amdgcn_mfma_f32_16x16x32_bf16(afr[kc], bf.v, acc, 0, 0, 0);
        }
        if (lr < NM) {
            #pragma unroll
            for (int r = 0; r < 4; r++)
                y[(long)(node0 + quad * 4 + r) * YS + lr] = acc[r];
        }
    } else {
        int t = (blockIdx.x - YB) * 256 + tid;   // t < 1152*128
        int kk = t >> 7;                         // kk' index 0..1151
        int o = t & 127;
        int ctt = kk / 144;
        int rem = kk - ctt * 144;
        int m = rem >> 4;
        int ci = rem & 15;
        float v = W[m * 16384 + o * 128 + ctt * 16 + ci];
        Wg[((kk >> 5) * 128 + o) * 32 + (kk & 31)] = __float2bfloat16(v);
    }
}

// ---------------- Kernel 2: fused, MFMA-everywhere ----------------
// 32 nodes/block, 512 threads (8 waves), LDS = 163,840 B:
//   [0,128K): per-node 4KB P slot ([ct8][kq4][j4][c16] bf16 subtiles for
//             ds_read_b64_tr_b16), overwritten IN PLACE by S' (bf16, 2304B,
//             kk' = ct*144+m*16+ci, XOR-swizzled by (n&7)<<4).
//   [128K,160K): per-node 1KB qT slot ([half2][kq4][j4][m16] bf16, hi/lo q).
// Phase A is barrier-free: deg via __ballot, wave w owns nodes 4w..4w+3 for
// gathers, q, tr-reads, MFMA and S' writes. One __syncthreads before phase B.
// Dual-bf16 q (deg_inv folded) keeps accuracy ~= the old f32-q path.
template<bool BF16G>
__global__ __launch_bounds__(512, 2) void fused_kernel(const float* __restrict__ x,
                                                       const __hip_bfloat16* __restrict__ xb,
                                                       const int* __restrict__ adj,
                                                       const float* __restrict__ y,
                                                       const float* __restrict__ cv,
                                                       const __hip_bfloat16* __restrict__ Wg,
                                                       const float* __restrict__ bv,
                                                       float* __restrict__ out) {
    __shared__ __align__(16) char smem[163840];

    int tid = threadIdx.x;
    int node0 = blockIdx.x * NPB;
    int b = node0 / NN;
    int n0 = node0 - b * NN;
    int ln = tid >> 4, k = tid & 15;                 // node-in-block, edge
    int lane = tid & 63, wv = tid >> 6;
    int lr = lane & 15, quad = lane >> 4;

    // ---- A1: adj, y rows, own-edge gather issue (16 uint4 = full 256B row) ----
    int a = adj[(n0 + ln) * NKN + k];
    long row = (long)(b * NN + ((a > 0) ? a - 1 : 0));

    const float* yn = y + (long)(node0 + ln) * YS;
    const float* ya = y + row * YS;
    float4 yn0 = *(const float4*)yn;
    float4 yn1 = *(const float4*)(yn + 4);
    float  yn8 = yn[8];
    float4 ya0 = *(const float4*)ya;
    float4 ya1 = *(const float4*)(ya + 4);
    float  ya8 = ya[8];

    uint4 pw[16];
    if (BF16G) {
        const uint4* xr = (const uint4*)(xb + row * NC);
        #pragma unroll
        for (int i = 0; i < 16; i++) pw[i] = xr[i];
    }

    // deg via ballot: node ln's 16 edge-threads are exactly this wave's quad
    unsigned long long mk = __ballot(a > 0);
    int d = (int)__popcll((mk >> (quad * 16)) & 0xFFFFull);
    float di = (d > 0) ? 1.f / (float)d : 0.f;

    // ---- A2: softmax (y-based), q' = softmax*deg_inv, dual-bf16 split ----
    float sel = (a > 0) ? 1.f : 0.f;
    float l[NM];
    l[0] = yn0.x - sel * ya0.x + cv[0];
    l[1] = yn0.y - sel * ya0.y + cv[1];
    l[2] = yn0.z - sel * ya0.z + cv[2];
    l[3] = yn0.w - sel * ya0.w + cv[3];
    l[4] = yn1.x - sel * ya1.x + cv[4];
    l[5] = yn1.y - sel * ya1.y + cv[5];
    l[6] = yn1.z - sel * ya1.z + cv[6];
    l[7] = yn1.w - sel * ya1.w + cv[7];
    l[8] = yn8   - sel * ya8   + cv[8];
    float mx = l[0];
    #pragma unroll
    for (int m = 1; m < NM; m++) mx = fmaxf(mx, l[m]);
    float e_[NM]; float sum = 0.f;
    #pragma unroll
    for (int m = 0; m < NM; m++) { e_[m] = expf(l[m] - mx); sum += e_[m]; }
    float qf = ((a > 0) ? (1.f / sum) : 0.f) * di;

    union { u16x8 v[2]; unsigned short s[16]; } H, L;
    #pragma unroll
    for (int m = 0; m < NM; m++) {
        float qv = e_[m] * qf;
        unsigned short hb = bfb(qv);
        union { unsigned short u; __hip_bfloat16 bb; } hh; hh.u = hb;
        float hf = __bfloat162float(hh.bb);
        H.s[m] = hb;
        L.s[m] = bfb(qv - hf);
    }
    #pragma unroll
    for (int m = NM; m < 16; m++) { H.s[m] = 0; L.s[m] = 0; }

    unsigned qo = QTOFF + (unsigned)(ln * 1024 + (k >> 2) * 128 + (k & 3) * 32);
    *(u16x8*)(smem + qo)        = H.v[0];
    *(u16x8*)(smem + qo + 16)   = H.v[1];
    *(u16x8*)(smem + qo + 512)  = L.v[0];
    *(u16x8*)(smem + qo + 528)  = L.v[1];

    // ---- A3: patch rows -> P subtiles (linear 16B stores) ----
    unsigned po = (unsigned)(ln * 4096 + (k >> 2) * 128 + (k & 3) * 32);
    if (BF16G) {
        #pragma unroll
        for (int i = 0; i < 16; i++)
            *(uint4*)(smem + po + (i >> 1) * 512 + (i & 1) * 16) = pw[i];
    } else {
        const float4* xf = (const float4*)(x + row * NC);
        #pragma unroll
        for (int i = 0; i < 16; i++) {
            float4 fa = xf[2 * i], fb2 = xf[2 * i + 1];
            union { u16x8 v; unsigned short s[8]; } o;
            o.s[0] = bfb(fa.x);  o.s[1] = bfb(fa.y);
            o.s[2] = bfb(fa.z);  o.s[3] = bfb(fa.w);
            o.s[4] = bfb(fb2.x); o.s[5] = bfb(fb2.y);
            o.s[6] = bfb(fb2.z); o.s[7] = bfb(fb2.w);
            *(u16x8*)(smem + po + (i >> 1) * 512 + (i & 1) * 16) = o.v;
        }
    }

    // fence: all qT/P stores land before any tr-read can be scheduled
    asm volatile("s_waitcnt lgkmcnt(0)" ::: "memory");
    __builtin_amdgcn_sched_barrier(0);

    unsigned sb = (unsigned)(unsigned long long)(uintptr_t)&smem[0];

    // ---- A4: per-wave MFMA over its 4 nodes; S' overwrites consumed P ----
    #pragma unroll
    for (int g = 0; g < 4; ++g) {
        int n = (wv << 2) + g;
        bf16x4 qa0, qa1;
        unsigned qaddr = sb + QTOFF + (unsigned)(n * 1024 + quad * 256 + lr * 8);
        asm volatile("ds_read_b64_tr_b16 %0, %2 offset:0\n\t"
                     "ds_read_b64_tr_b16 %1, %2 offset:128"
                     : "=&v"(qa0), "=&v"(qa1) : "v"(qaddr));
        bf16x4 pb0[8], pb1[8];
        unsigned paddr = sb + (unsigned)(n * 4096 + (quad & 1) * 256 + lr * 8);
        #pragma unroll
        for (int t = 0; t < 8; ++t)
            asm volatile("ds_read_b64_tr_b16 %0, %2 offset:%c3\n\t"
                         "ds_read_b64_tr_b16 %1, %2 offset:%c4"
                         : "=&v"(pb0[t]), "=&v"(pb1[t])
                         : "v"(paddr), "i"(t * 512), "i"(t * 512 + 128));
        asm volatile("s_waitcnt lgkmcnt(0)" ::: "memory");
        __builtin_amdgcn_sched_barrier(0);

        frg8 af; af.h[0] = qa0; af.h[1] = qa1;
        unsigned swz = (unsigned)((n & 7) << 4);
        unsigned sbase = (unsigned)(n * 4096);
        #pragma unroll
        for (int t = 0; t < 8; ++t) {
            frg8 bf_; bf_.h[0] = pb0[t]; bf_.h[1] = pb1[t];
            f32x4 acc = (f32x4){0.f, 0.f, 0.f, 0.f};
            acc = __builtin_amdgcn_mfma_f32_16x16x32_bf16(af.v, bf_.v, acc, 0, 0, 0);
            #pragma unroll
            for (int r = 0; r < 4; ++r) {
                int m = quad * 4 + r;
                if (m < 9) {
                    unsigned off = ((unsigned)(t * 288 + m * 32 + lr * 2)) ^ swz;
                    *(short*)(smem + sbase + off) = (short)bfb(acc[r]);
                }
            }
        }
    }

    __syncthreads();                                   // S' ready block-wide

    // ---- phase B: 32x1152 @ 1152x128, current verified structure ----
    const short* wg = reinterpret_cast<const short*>(Wg);
    f32x4 acc0 = (f32x4){0.f, 0.f, 0.f, 0.f};
    f32x4 acc1 = (f32x4){0.f, 0.f, 0.f, 0.f};
    unsigned swzB = (unsigned)((lr & 7) << 4);         // (16+lr)&7 == lr&7
    #pragma unroll 9
    for (int kc = 0; kc < 36; kc++) {
        bf16x8 bfrag = *(const bf16x8*)(wg + ((kc * 128) + wv * 16 + lr) * 32 + quad * 8);
        unsigned ao = ((unsigned)(kc * 64 + quad * 16)) ^ swzB;
        bf16x8 a0 = *(const bf16x8*)(smem + (unsigned)(lr * 4096) + ao);
        bf16x8 a1 = *(const bf16x8*)(smem + (unsigned)((16 + lr) * 4096) + ao);
        acc0 = __builtin_amdgcn_mfma_f32_16x16x32_bf16(a0, bfrag, acc0, 0, 0, 0);
        acc1 = __builtin_amdgcn_mfma_f32_16x16x32_bf16(a1, bfrag, acc1, 0, 0, 0);
    }

    int col = wv * 16 + lr;
    float bb = bv[col];
    int rbase = node0 + quad * 4;
    #pragma unroll
    for (int r = 0; r < 4; r++) {
        out[(long)(rbase + r) * NO + col]      = acc0[r] + bb;
        out[(long)(rbase + 16 + r) * NO + col] = acc1[r] + bb;
    }
}

extern "C" void kernel_launch(void* const* d_in, const int* in_sizes, int n_in,
                              void* d_out, int out_size, void* d_ws, size_t ws_size,
                              hipStream_t stream) {
    const float* x   = (const float*)d_in[0];   // (B,N,C)
    const int*   adj = (const int*)  d_in[1];   // (N,K)
    const float* W   = (const float*)d_in[2];   // (M,O,C)
    const float* bv  = (const float*)d_in[3];   // (O,)
    const float* u   = (const float*)d_in[4];   // (M,C)
    const float* cv  = (const float*)d_in[5];   // (M,)
    float* out = (float*)d_out;

    char* ws = (char*)d_ws;
    float* y = (float*)ws;                                     // 1,920,000 B
    __hip_bfloat16* Wg = (__hip_bfloat16*)(ws + 1920000);      //   294,912 B
    __hip_bfloat16* xb = (__hip_bfloat16*)(ws + 2214912);      // 10,240,000 B
    bool use_xb = (ws_size >= (size_t)12454912);

    prep_kernel<<<YB + 576, 256, 0, stream>>>(x, u, W, y, use_xb ? xb : nullptr, Wg,
                                              use_xb ? 1 : 0);
    if (use_xb)
        fused_kernel<true><<<NR / NPB, 512, 0, stream>>>(x, xb, adj, y, cv, Wg, bv, out);
    else
        fused_kernel<false><<<NR / NPB, 512, 0, stream>>>(x, xb, adj, y, cv, Wg, bv, out);
}